// Round 7
// baseline (131.089 us; speedup 1.0000x reference)
//
#include <hip/hip_runtime.h>
#include <math.h>

#define BINS 10

// Problem constants: BATCH=8388608, NUM_CLASSES=2
constexpr int   NPAIRS = 4194304;       // float4 quads (2 rows x 2 classes each)
constexpr float NTOT_F = 16777216.0f;   // BATCH * NUM_CLASSES

constexpr int G1     = 2048;
constexpr int BLK    = 256;
constexpr int STRIDE = G1 * BLK;        // 524288
constexpr int ITERS  = NPAIRS / STRIDE; // 8 exact -> no tail

// Workspace: blk_pair[slot*G1 + block], slot 0..8 = bin sums/counts,
// slot 9 = {total log2-bce sum, unused}. 160 KB.
constexpr size_t WS_PAIR = 0;

struct alignas(8) Pair { float s; unsigned c; };

// Hot path lessons: LDS atomics ~10x trap (R4); LDS RMW latency-chains (R2/3);
// VGPR cndmask accumulators are the fast path (R5). This round: counts moved to
// SALU via popc(ballot) on the SAME compare the cndmask uses; bin 9 recovered
// algebraically from the total, so the select loop is 9 bins.
__device__ __forceinline__ void proc(float x, bool y1,
                                     float* __restrict__ acc, float& sumL,
                                     unsigned* __restrict__ cw) {
    // z = (y==1) ? -x : x ; t = e^z ; u = 1+t
    // g = |sigmoid(x)-y| = t/u ; bce = max(x,0)-x*y+log1p(e^-|x|) = ln(u)
    float z = y1 ? -x : x;
    float t = __builtin_amdgcn_exp2f(z * 1.4426950408889634f);
    float u = 1.0f + t;
    float g = t * __builtin_amdgcn_rcpf(u);
    int   b = (int)(g * 9.9999f);        // g in [0,1] -> trunc == floor
    b = b < 9 ? b : 9;                   // clamp (rcp rounding safety)
    float l = __builtin_amdgcn_logf(u);  // log2(u); ln2 applied once at the end
    sumL += l;                           // bin9 sum = sumL - sum(bins 0..8)
#pragma unroll
    for (int i = 0; i < BINS - 1; ++i) {
        bool hit = (b == i);
        acc[i] += hit ? l : 0.0f;                        // v_cmp + v_cndmask + v_add
        cw[i]  += (unsigned)__popcll(__ballot(hit));     // s_bcnt1 + s_add (SALU, free lane)
    }
}

__global__ __launch_bounds__(BLK) void ghm_main(const float4* __restrict__ x4,
                                                const int2*   __restrict__ t2,
                                                Pair*         __restrict__ blk_pair) {
    const int tid  = threadIdx.x;
    const int lane = tid & 63;
    const int wave = tid >> 6;

    float acc[BINS - 1];
#pragma unroll
    for (int b = 0; b < BINS - 1; ++b) acc[b] = 0.0f;
    float sumL = 0.0f;
    unsigned cw[BINS - 1];               // wave-uniform (SGPR) per-wave counts
#pragma unroll
    for (int b = 0; b < BINS - 1; ++b) cw[b] = 0u;

    const int base = blockIdx.x * BLK + tid;
#pragma unroll
    for (int k = 0; k < ITERS; ++k) {
        float4 xv = x4[base + k * STRIDE];
        int2   tv = t2[base + k * STRIDE];
        // element (row, c): y = (target[row] == c)
        proc(xv.x, tv.x == 0, acc, sumL, cw);
        proc(xv.y, tv.x == 1, acc, sumL, cw);
        proc(xv.z, tv.y == 0, acc, sumL, cw);
        proc(xv.w, tv.y == 1, acc, sumL, cw);
    }

    // ---- block reduce: LDS columns (conflict-free), not 120 bpermutes ----
    __shared__ float    lsum[BINS * BLK];   // slot 9 = sumL; 10240 B
    __shared__ unsigned lcnt[4][BINS - 1];  // per-wave SGPR counts
#pragma unroll
    for (int b = 0; b < BINS - 1; ++b) lsum[b * BLK + tid] = acc[b];
    lsum[9 * BLK + tid] = sumL;
    if (lane == 0) {
#pragma unroll
        for (int b = 0; b < BINS - 1; ++b) lcnt[wave][b] = cw[b];
    }
    __syncthreads();

    // wave w reduces slots {w, w+4, w+8}: 4 strided reads + 6-step shuffle tree
    for (int b = wave; b < BINS; b += 4) {
        float s = lsum[b * BLK + lane]       + lsum[b * BLK + lane + 64]
                + lsum[b * BLK + lane + 128] + lsum[b * BLK + lane + 192];
        for (int off = 32; off > 0; off >>= 1) s += __shfl_down(s, off, 64);
        if (lane == 0) {
            unsigned c = 0u;
            if (b < BINS - 1) c = lcnt[0][b] + lcnt[1][b] + lcnt[2][b] + lcnt[3][b];
            blk_pair[b * G1 + blockIdx.x] = Pair{s, c};   // slot-major for final
        }
    }
}

// Final: 10 waves (one per slot); fully-unrolled independent loads; f64 shuffle
// reduce; thread 0 recovers bin 9 (S9 = total - sum, C9 = N - count), forms beta
// per reference fp32 arithmetic, and writes the mean. Deterministic.
__global__ __launch_bounds__(640) void ghm_final(const Pair* __restrict__ blk_pair,
                                                 float*      __restrict__ out) {
    const int wave = threadIdx.x >> 6;   // 0..9 = slot
    const int lane = threadIdx.x & 63;
    double s = 0.0, c = 0.0;
#pragma unroll
    for (int k = 0; k < G1 / 64; ++k) {
        Pair p = blk_pair[wave * G1 + k * 64 + lane];
        s += (double)p.s;
        c += (double)p.c;
    }
    for (int off = 32; off > 0; off >>= 1) {
        s += __shfl_down(s, off, 64);
        c += __shfl_down(c, off, 64);
    }
    __shared__ double Sb[BINS], Cb[BINS];
    if (lane == 0) { Sb[wave] = s; Cb[wave] = c; }
    __syncthreads();
    if (threadIdx.x == 0) {
        double s9 = Sb[9], c9 = (double)NTOT_F;
#pragma unroll
        for (int b = 0; b < BINS - 1; ++b) { s9 -= Sb[b]; c9 -= Cb[b]; }
        Sb[9] = s9; Cb[9] = c9;
        float nonempty = 0.0f;
#pragma unroll
        for (int b = 0; b < BINS; ++b) nonempty += (Cb[b] > 0.0) ? 1.0f : 0.0f;
        double tot = 0.0;
#pragma unroll
        for (int b = 0; b < BINS; ++b) {
            float gd   = fmaxf((float)Cb[b] * nonempty, 0.0001f);  // ref fp32 math
            float beta = NTOT_F / gd;
            tot += (double)beta * Sb[b];
        }
        // bce sums kept in log2; apply ln2 once, then mean
        out[0] = (float)(tot * 0.693147180559945309 / (double)NTOT_F);
    }
}

extern "C" void kernel_launch(void* const* d_in, const int* in_sizes, int n_in,
                              void* d_out, int out_size, void* d_ws, size_t ws_size,
                              hipStream_t stream) {
    const float4* x4 = (const float4*)d_in[0];   // [B,2] fp32 -> 2 rows per float4
    const int2*   t2 = (const int2*)d_in[1];     // int32 targets -> 2 rows per int2

    Pair*  blk_pair = (Pair*)((char*)d_ws + WS_PAIR);
    float* out      = (float*)d_out;

    ghm_main <<<G1, BLK, 0, stream>>>(x4, t2, blk_pair);
    ghm_final<<<1, 640, 0, stream>>>(blk_pair, out);
}